// Round 10
// baseline (2026.463 us; speedup 1.0000x reference)
//
#include <hip/hip_runtime.h>
#include <cmath>

// GaussCRF on MI355X — round 17: msg fused into combine.
// B=2, C=21, H=W=512, blur=4 -> h=w=128, K=11 (121 shifts), 5 iterations.
//
// r16 post-mortem: per-block g recompute cost more than the g round-trip
// (262->282): 99 scattered cf loads + 66 serial expf/thread, duplicated x2
// across channel-halves. Reverted. Budget at r15: ~44us dispatch gaps +
// msg ~25us/dispatch of unhidden LDS/global latency.
// r17: FUSE msg into combine (iter_k). combine streams 44 MB unary
// (BW-bound); msg is LDS-bound -> fused they overlap. Cost: 1.875x msg
// redundancy (6x10 halo vs 4x8 owned) -- cheap, msg throughput is ~9us.
//  * gauss_k writes g halo-tiled: gh[(b*32+tx)*16+ty][ij][rr*10+cl] at
//    CLAMPED halo coords (29.7 MB, coalesced write; per-block 29 KB slice
//    is L1-resident during the tap loop).
//  * iter_k: stage p halo 16x20x6 f4 zero-padded, stride-7 f4 (banks
//    spread, 28k%32 cycles all 8 quads); per item (pos,quad) accumulate
//    121 taps in r7-validated ij order; barrier; overlay ms=[pos*24+c]
//    onto LDS; barrier; combine epilogue VERBATIM (reads msf).
//  * dispatches 11 -> 7.  prep_k unchanged.  absmax expect ~0.25.

#define BB 2
#define CC 21
#define HH 512
#define WW 512
#define HP 128
#define WP 128
#define KF 11
#define SPAN 5
#define NITER 5
#define PLF (HH*WW)
#define PLP (HP*WP)
#define PC 24       // packed channel stride (floats), 96 B = 6 x float4
#define GH_T (121*60)   // per-tile g halo values
#define HSTR 7      // f4 stride per (h,col) cell in p-halo LDS
#define PTN4 (16*20*HSTR)   // 2240 float4 = 35.8 KB

// blocks 0..1023: init tiles; blocks 1024..1407: img pool.
__global__ __launch_bounds__(256) void prep_k(const float* __restrict__ img,
                                              const float* __restrict__ col_schan,
                                              const float* __restrict__ unary,
                                              float* __restrict__ cf,
                                              float* __restrict__ p) {
    int bid = blockIdx.x;
    int t = threadIdx.x;
    if (bid >= 1024) {                       // ---- pool img -> cf ----
        int idx = (bid - 1024)*256 + t;      // < BB*3*PLP = 98304 exactly
        int Y  = idx & (WP-1);
        int X  = (idx >> 7) & (HP-1);
        int bc = idx >> 14;
        const float* base = img + ((size_t)bc*HH + X*4)*WW + Y*4;
        float s = 0.f;
        #pragma unroll
        for (int i = 0; i < 4; ++i)
            #pragma unroll
            for (int j = 0; j < 4; ++j)
                s += base[i*WW + j];
        cf[idx] = s * (1.f/16.f) * col_schan[0];
        return;
    }
    // ---- p0 = 4x4 pool of log_softmax(unary), packed [b][X][Y][24] ----
    int b = bid >> 9, rem = bid & 511, tx = rem >> 4, ty = rem & 15;
    int row = t >> 4, c2 = t & 15;
    int x = tx*16 + row, y = ty*32 + 2*c2;
    size_t base = (size_t)b*CC*PLF + (size_t)x*WW + y;
    float va[CC], vb[CC];
    float ma = -1e30f, mb = -1e30f;
    #pragma unroll
    for (int c = 0; c < CC; ++c) {
        float2 u = *(const float2*)(unary + base + (size_t)c*PLF);
        va[c] = u.x; vb[c] = u.y;
        ma = fmaxf(ma, u.x); mb = fmaxf(mb, u.y);
    }
    float sa = 0.f, sb = 0.f;
    #pragma unroll
    for (int c = 0; c < CC; ++c) { sa += expf(va[c]-ma); sb += expf(vb[c]-mb); }
    float lsa = ma + logf(sa), lsb = mb + logf(sb);
    float out[PC];
    #pragma unroll
    for (int c = 0; c < PC; ++c) out[c] = 0.f;
    #pragma unroll
    for (int c = 0; c < CC; ++c) {
        float sm = (va[c]-lsa) + (vb[c]-lsb);
        sm += __shfl_xor(sm, 1);
        sm += __shfl_xor(sm, 16);
        sm += __shfl_xor(sm, 32);
        out[c] = sm * (1.f/16.f);
    }
    int lane = t & 63;
    if ((lane & 49) == 0) {                  // bits {0,4,5} == 0
        int X = tx*4 + (t >> 6), Y = ty*8 + (c2 >> 1);
        float4* dst = (float4*)(p + ((size_t)(b*HP + X)*WP + Y)*PC);
        const float4* src = (const float4*)out;
        dst[0]=src[0]; dst[1]=src[1]; dst[2]=src[2];
        dst[3]=src[3]; dst[4]=src[4]; dst[5]=src[5];
    }
}

// g halo-tiled: gh[tile][ij][pos], tile = (b*32+tx)*16+ty, pos = rr*10+cl
// value = g at CLAMPED pooled coords (clamp(tx*4-1+rr), clamp(ty*8-1+cl)).
__global__ __launch_bounds__(256) void gauss_k(const float* __restrict__ cf,
                                               const float* __restrict__ pos_sdims,
                                               const float* __restrict__ pos_compat,
                                               const float* __restrict__ col_compat,
                                               float* __restrict__ gh) {
    int tile = blockIdx.x;                   // 0..1023
    int ty = tile & 15, tx = (tile >> 4) & 31, b = tile >> 9;
    const float* cb = cf + (size_t)b*3*PLP;
    const float ps  = 4.f * pos_sdims[0];
    const float pcm = pos_compat[0], ccm = col_compat[0];
    for (int e = threadIdx.x; e < GH_T; e += 256) {
        int ij = e / 60, pos = e % 60;
        int rr = pos / 10, cl = pos % 10;
        int Xc = tx*4 - 1 + rr; Xc = Xc < 0 ? 0 : (Xc > HP-1 ? HP-1 : Xc);
        int Yc = ty*8 - 1 + cl; Yc = Yc < 0 ? 0 : (Yc > WP-1 ? WP-1 : Yc);
        int di = ij / KF - SPAN;
        int dj = ij % KF - SPAN;
        int Xn = Xc + di, Yn = Yc + dj;
        float val = 0.f;
        if (Xn >= 0 && Xn < HP && Yn >= 0 && Yn < WP) {
            int o0 = Xc*WP + Yc, o = Xn*WP + Yn;
            float d0 = cb[o]         - cb[o0];
            float d1 = cb[PLP + o]   - cb[PLP + o0];
            float d2 = cb[2*PLP + o] - cb[2*PLP + o0];
            float cd2 = d0*d0 + d1*d1 + d2*d2;
            float pd2 = ps*ps * (float)(di*di + dj*dj);
            val = pcm * expf(-0.5f*pd2) + ccm * expf(-0.5f*cd2);
        }
        gh[(size_t)tile*GH_T + e] = val;
    }
}

// iter_k: msg (6x10 pooled halo, in-block) + bilinear + combine + pool.
// grid (16, 32, BB): tx = blockIdx.y (0..31, 16 rows), ty = blockIdx.x.
__global__ __launch_bounds__(256, 4) void iter_k(const float* __restrict__ p,
                                                 const float* __restrict__ gh,
                                                 const float* __restrict__ unary,
                                                 const float* __restrict__ weight,
                                                 float* __restrict__ pnew,
                                                 float* __restrict__ pred,
                                                 int last) {
    int b = blockIdx.z, tx = blockIdx.y, ty = blockIdx.x;
    int t = threadIdx.x;
    __shared__ __align__(16) float4 sh4[PTN4];      // 35.8 KB
    // ---- stage p halo: pooled rows tx*4-6..+9, cols ty*8-6..+13, zero-pad
    const float4* pg = (const float4*)(p + (size_t)b*PLP*PC);
    for (int e = t; e < 16*20*6; e += 256) {
        int q = e % 6, pos2 = e / 6;
        int h = pos2 / 20, col = pos2 % 20;
        int gX = tx*4 - 6 + h, gY = ty*8 - 6 + col;
        float4 v = {0.f,0.f,0.f,0.f};
        if (gX >= 0 && gX < HP && gY >= 0 && gY < WP)
            v = pg[(size_t)(gX*WP + gY)*6 + q];
        sh4[pos2*HSTR + q] = v;
    }
    __syncthreads();
    // ---- msg for halo positions: item = pos*6 + q (360 items) ----
    const float* ght = gh + (size_t)((b*32 + tx)*16 + ty)*GH_T;
    float4 a0 = {0.f,0.f,0.f,0.f}, a1 = {0.f,0.f,0.f,0.f};
    {   // item A = t  (t < 360 always)
        int pos = t / 6, q = t % 6;
        int rr = pos / 10, cl = pos % 10;
        int Xc = tx*4 - 1 + rr; Xc = Xc < 0 ? 0 : (Xc > HP-1 ? HP-1 : Xc);
        int Yc = ty*8 - 1 + cl; Yc = Yc < 0 ? 0 : (Yc > WP-1 ? WP-1 : Yc);
        int hb = Xc - tx*4 + 1, wb = Yc - ty*8 + 1;
        const float* gp = ght + pos;
        for (int dd = 0; dd < KF; ++dd) {
            const float4* prow = sh4 + ((hb + dd)*20 + wb)*HSTR + q;
            const float* grow = gp + (size_t)(dd*KF)*60;
            #pragma unroll
            for (int dj = 0; dj < KF; ++dj) {
                float gv = grow[(size_t)dj*60];
                float4 pv = prow[dj*HSTR];
                a0.x = fmaf(gv, pv.x, a0.x);
                a0.y = fmaf(gv, pv.y, a0.y);
                a0.z = fmaf(gv, pv.z, a0.z);
                a0.w = fmaf(gv, pv.w, a0.w);
            }
        }
    }
    if (t < 104) {   // item B = t + 256
        int it2 = t + 256;
        int pos = it2 / 6, q = it2 % 6;
        int rr = pos / 10, cl = pos % 10;
        int Xc = tx*4 - 1 + rr; Xc = Xc < 0 ? 0 : (Xc > HP-1 ? HP-1 : Xc);
        int Yc = ty*8 - 1 + cl; Yc = Yc < 0 ? 0 : (Yc > WP-1 ? WP-1 : Yc);
        int hb = Xc - tx*4 + 1, wb = Yc - ty*8 + 1;
        const float* gp = ght + pos;
        for (int dd = 0; dd < KF; ++dd) {
            const float4* prow = sh4 + ((hb + dd)*20 + wb)*HSTR + q;
            const float* grow = gp + (size_t)(dd*KF)*60;
            #pragma unroll
            for (int dj = 0; dj < KF; ++dj) {
                float gv = grow[(size_t)dj*60];
                float4 pv = prow[dj*HSTR];
                a1.x = fmaf(gv, pv.x, a1.x);
                a1.y = fmaf(gv, pv.y, a1.y);
                a1.z = fmaf(gv, pv.z, a1.z);
                a1.w = fmaf(gv, pv.w, a1.w);
            }
        }
    }
    __syncthreads();                 // all p-halo reads done
    sh4[t] = a0;                     // overlay: msf[pos*24 + c]
    if (t < 104) sh4[t + 256] = a1;
    __syncthreads();
    const float* msf = (const float*)sh4;

    // ---- epilogue: combine_k verbatim (ms[c][i0][j0] -> msf[(i0*10+j0)*24+c])
    int row = t >> 4, c2 = t & 15;
    int x = tx*16 + row, y = ty*32 + 2*c2;
    size_t base = (size_t)b*CC*PLF + (size_t)x*WW + y;
    int rs = row & 3, q = row >> 2;
    float fx = (rs == 0) ? 0.625f : (rs == 1) ? 0.875f : (rs == 2) ? 0.125f : 0.375f;
    int i0 = q + (rs >> 1);
    int cs0 = (2*c2) & 3;                    // 0 or 2; pixel pair shares j0
    int qc  = (2*c2) >> 2;
    float fya = (cs0 == 0) ? 0.625f : 0.125f;
    float fyb = (cs0 == 0) ? 0.875f : 0.375f;
    int j0 = qc + (cs0 >> 1);
    float gx0 = 1.f - fx;
    float wt = weight[0], uw = 1.f - wt;     // UNARY_WEIGHT = 1.0
    float va[CC], vb[CC];
    float ma = -1e30f, mbx = -1e30f;
    #pragma unroll
    for (int c = 0; c < CC; ++c) {
        float2 u = *(const float2*)(unary + base + (size_t)c*PLF);
        va[c] = u.x; vb[c] = u.y;
        ma = fmaxf(ma, u.x); mbx = fmaxf(mbx, u.y);
    }
    float sa = 0.f, sb = 0.f;
    #pragma unroll
    for (int c = 0; c < CC; ++c) { sa += expf(va[c]-ma); sb += expf(vb[c]-mbx); }
    float lsa = ma + logf(sa), lsb = mbx + logf(sb);
    #pragma unroll
    for (int c = 0; c < CC; ++c) {
        float m00 = msf[(i0*10 + j0)*24 + c],     m01 = msf[(i0*10 + j0+1)*24 + c];
        float m10 = msf[((i0+1)*10 + j0)*24 + c], m11 = msf[((i0+1)*10 + j0+1)*24 + c];
        float ca = gx0*m00 + fx*m10;         // column j0 blended in x
        float cb = gx0*m01 + fx*m11;         // column j0+1 blended in x
        float mua = (1.f-fya)*ca + fya*cb;
        float mub = (1.f-fyb)*ca + fyb*cb;
        va[c] = uw*(va[c]-lsa) + wt*mua;
        vb[c] = uw*(vb[c]-lsb) + wt*mub;
    }
    if (last) {
        #pragma unroll
        for (int c = 0; c < CC; ++c) {
            float2 o; o.x = va[c]; o.y = vb[c];
            *(float2*)(pred + base + (size_t)c*PLF) = o;
        }
    } else {
        float mma = -1e30f, mmb = -1e30f;
        #pragma unroll
        for (int c = 0; c < CC; ++c) { mma = fmaxf(mma, va[c]); mmb = fmaxf(mmb, vb[c]); }
        float ssa = 0.f, ssb = 0.f;
        #pragma unroll
        for (int c = 0; c < CC; ++c) {
            va[c] = expf(va[c]-mma); ssa += va[c];
            vb[c] = expf(vb[c]-mmb); ssb += vb[c];
        }
        float ia = 1.f/ssa, ib = 1.f/ssb;
        float out[PC];
        #pragma unroll
        for (int c = 0; c < PC; ++c) out[c] = 0.f;
        #pragma unroll
        for (int c = 0; c < CC; ++c) {
            float sm = va[c]*ia + vb[c]*ib;
            sm += __shfl_xor(sm, 1);
            sm += __shfl_xor(sm, 16);
            sm += __shfl_xor(sm, 32);
            out[c] = sm * (1.f/16.f);
        }
        int lane = t & 63;
        if ((lane & 49) == 0) {
            int X = tx*4 + (t >> 6), Y = ty*8 + (c2 >> 1);
            float4* dst = (float4*)(pnew + ((size_t)(b*HP + X)*WP + Y)*PC);
            const float4* src = (const float4*)out;
            dst[0]=src[0]; dst[1]=src[1]; dst[2]=src[2];
            dst[3]=src[3]; dst[4]=src[4]; dst[5]=src[5];
        }
    }
}

extern "C" void kernel_launch(void* const* d_in, const int* in_sizes, int n_in,
                              void* d_out, int out_size, void* d_ws, size_t ws_size,
                              hipStream_t stream) {
    const float* unary      = (const float*)d_in[0];
    const float* img        = (const float*)d_in[1];
    const float* pos_sdims  = (const float*)d_in[2];
    const float* col_schan  = (const float*)d_in[3];
    const float* pos_compat = (const float*)d_in[4];
    const float* col_compat = (const float*)d_in[5];
    const float* weight     = (const float*)d_in[6];
    float* pred = (float*)d_out;
    float* ws   = (float*)d_ws;

    size_t o = 0;
    float* cf  = ws + o;  o += (size_t)BB*3*PLP;        // 0.4 MB
    float* gh  = ws + o;  o += (size_t)1024*GH_T;       // 29.7 MB
    float* pA  = ws + o;  o += (size_t)BB*PLP*PC;       // 3.1 MB packed
    float* pB  = ws + o;
    float* pbuf[2] = {pA, pB};

    const int TB = 256;
    hipLaunchKernelGGL(prep_k, dim3(1408), dim3(TB), 0, stream,
                       img, col_schan, unary, cf, pA);
    hipLaunchKernelGGL(gauss_k, dim3(1024), dim3(TB), 0, stream,
                       cf, pos_sdims, pos_compat, col_compat, gh);
    for (int it = 0; it < NITER; ++it) {
        hipLaunchKernelGGL(iter_k, dim3(16, 32, BB), dim3(256), 0, stream,
                           pbuf[it & 1], gh, unary, weight,
                           pbuf[(it + 1) & 1], pred,
                           (it == NITER-1) ? 1 : 0);
    }
}